// Round 11
// baseline (374.274 us; speedup 1.0000x reference)
//
#include <hip/hip_runtime.h>

#define N_NODES 100000
#define N_EDGES 1600000
#define H 128

#define NB 391        // dst buckets of 256 nodes: ceil(100000/256)
#define P1_EPB 4096   // edges per pass-1 block
#define P1_BLOCKS ((N_EDGES + P1_EPB - 1) / P1_EPB)   // 391
#define P2_CAP 6144   // bucket capacity (mean 4096, sigma~64)

typedef unsigned short u16;
typedef unsigned int u32;
typedef short bf16x8 __attribute__((ext_vector_type(8)));
typedef float f32x4 __attribute__((ext_vector_type(4)));

static __device__ __forceinline__ u16 f2bf(float f) {  // RNE float->bf16
    u32 u = __float_as_uint(f);
    u += 0x7fffu + ((u >> 16) & 1u);
    return (u16)(u >> 16);
}

// ---------------- CSR build ----------------

__global__ void zero_ints(int* __restrict__ p, int n) {
    int i = blockIdx.x * blockDim.x + threadIdx.x;
    if (i < n) p[i] = 0;
}

__global__ void count_deg(const int* __restrict__ dst, int* __restrict__ deg, int e) {
    int i = blockIdx.x * blockDim.x + threadIdx.x;
    if (i < e) atomicAdd(&deg[dst[i]], 1);
}

__global__ void scan_blocks(const int* __restrict__ deg, int* __restrict__ rowstart,
                            int* __restrict__ bsums, int n) {
    __shared__ int s[1024];
    int t = threadIdx.x;
    int i = blockIdx.x * 1024 + t;
    int v = (i < n) ? deg[i] : 0;
    s[t] = v;
    __syncthreads();
    for (int off = 1; off < 1024; off <<= 1) {
        int add = (t >= off) ? s[t - off] : 0;
        __syncthreads();
        s[t] += add;
        __syncthreads();
    }
    if (i < n) rowstart[i] = s[t] - v;   // exclusive
    if (t == 1023) bsums[blockIdx.x] = s[t];
}

__global__ void scan_sums(const int* __restrict__ bsums, int* __restrict__ boffs, int nb) {
    __shared__ int s[128];
    int t = threadIdx.x;
    int v = (t < nb) ? bsums[t] : 0;
    s[t] = v;
    __syncthreads();
    for (int off = 1; off < 128; off <<= 1) {
        int add = (t >= off) ? s[t - off] : 0;
        __syncthreads();
        s[t] += add;
        __syncthreads();
    }
    if (t < nb) boffs[t] = s[t] - v;     // exclusive
}

__global__ void add_offsets(int* __restrict__ rowstart, const int* __restrict__ boffs, int n) {
    int i = blockIdx.x * blockDim.x + threadIdx.x;
    if (i < n) rowstart[i] += boffs[i >> 10];
}

__global__ void init_bcur(const int* __restrict__ rowstart, int* __restrict__ bcur) {
    int b = blockIdx.x * 256 + threadIdx.x;
    if (b < NB) bcur[b] = rowstart[b << 8];
}

// Pass 1: bin edges by dst>>8 into bucket-contiguous csr ranges (packed u32:
// bits[24:17]=dst&255, bits[16:0]=src). LDS-staged so global writes are
// slot-ordered bucket runs (R6/R7 lesson: raw 4B scatter = 64B partial-line
// HBM writebacks; XCD L2s can't merge).
__global__ __launch_bounds__(1024) void p1_bin(
    const int* __restrict__ src, const int* __restrict__ dst,
    int* __restrict__ bcur, u32* __restrict__ csrp)
{
    __shared__ int s_cnt[NB];      // histogram, then running local cursor
    __shared__ int s_lstart[NB];   // block-local exclusive start per bucket
    __shared__ int s_gbase[NB];    // reserved global base per bucket
    __shared__ int s_scan[512];
    __shared__ u32 s_val[P1_EPB];
    __shared__ u32 s_gaddr[P1_EPB];

    const int t = threadIdx.x;
    const int e0 = blockIdx.x * P1_EPB;
    const int ecnt = min(P1_EPB, N_EDGES - e0);

    for (int i = t; i < NB; i += 1024) s_cnt[i] = 0;
    __syncthreads();
    for (int i = t; i < ecnt; i += 1024)
        atomicAdd(&s_cnt[dst[e0 + i] >> 8], 1);
    __syncthreads();

    int v = (t < NB) ? s_cnt[t] : 0;
    if (t < 512) s_scan[t] = v;
    __syncthreads();
    for (int off = 1; off < 512; off <<= 1) {
        int add = (t < 512 && t >= off) ? s_scan[t - off] : 0;
        __syncthreads();
        if (t < 512) s_scan[t] += add;
        __syncthreads();
    }
    if (t < NB) {
        int ls = s_scan[t] - v;   // exclusive
        s_lstart[t] = ls;
        s_gbase[t] = (v > 0) ? atomicAdd(&bcur[t], v) : 0;
        s_cnt[t] = ls;            // becomes running cursor
    }
    __syncthreads();

    for (int i = t; i < ecnt; i += 1024) {
        int d = dst[e0 + i];
        int s = src[e0 + i];
        int b = d >> 8;
        int slot = atomicAdd(&s_cnt[b], 1);
        s_val[slot]   = ((u32)(d & 255) << 17) | (u32)s;
        s_gaddr[slot] = (u32)(s_gbase[b] + (slot - s_lstart[b]));
    }
    __syncthreads();
    for (int i = t; i < ecnt; i += 1024)
        csrp[s_gaddr[i]] = s_val[i];
}

// Pass 2: one block per bucket; bin packed entries to exact per-node order in
// LDS, write back fully coalesced. In-place safe (load barrier store).
__global__ __launch_bounds__(1024) void p2_scatter(
    const int* __restrict__ rowstart, int* __restrict__ csr)
{
    __shared__ int s_cur[256];
    __shared__ u32 s_out[P2_CAP];
    const int b = blockIdx.x;
    const int t = threadIdx.x;
    const int n0 = b << 8;
    const int s0 = rowstart[n0];
    const int s1 = (b == NB - 1) ? N_EDGES : rowstart[n0 + 256];
    const int cnt = s1 - s0;

    if (t < 256) {
        int node = n0 + t;
        s_cur[t] = (node < N_NODES) ? (rowstart[node] - s0) : cnt;
    }
    __syncthreads();
    for (int i = t; i < cnt; i += 1024) {
        u32 p = (u32)csr[s0 + i];
        int pos = atomicAdd(&s_cur[p >> 17], 1);
        s_out[pos] = p & 0x1FFFFu;
    }
    __syncthreads();
    for (int i = t; i < cnt; i += 1024)
        csr[s0 + i] = (int)s_out[i];
}

// ---------------- casts ----------------

__global__ __launch_bounds__(256) void cast_x(const float* __restrict__ in,
                                              u16* __restrict__ out) {
    int i = blockIdx.x * 256 + threadIdx.x;   // 1.6M threads x 8 elems
    const float4 v0 = *(const float4*)(in + (size_t)i * 8);
    const float4 v1 = *(const float4*)(in + (size_t)i * 8 + 4);
    u16 o[8];
    o[0]=f2bf(v0.x); o[1]=f2bf(v0.y); o[2]=f2bf(v0.z); o[3]=f2bf(v0.w);
    o[4]=f2bf(v1.x); o[5]=f2bf(v1.y); o[6]=f2bf(v1.z); o[7]=f2bf(v1.w);
    *(bf16x8*)(out + (size_t)i * 8) = *(bf16x8*)o;
}

__global__ __launch_bounds__(256) void cast_w(const float* __restrict__ w1l,
                                              const float* __restrict__ w1r,
                                              const float* __restrict__ w2l,
                                              const float* __restrict__ w2r,
                                              u16* __restrict__ out) {
    int i = blockIdx.x * 256 + threadIdx.x;   // 65536 threads
    int mat = i >> 14, idx = i & 16383;
    const float* s = (mat == 0) ? w1l : (mat == 1) ? w1r : (mat == 2) ? w2l : w2r;
    out[i] = f2bf(s[idx]);
}

// ---------------- Aggregation: wave/node, 8-wide MLP, bf16 in/out ----------------

__global__ __launch_bounds__(256) void agg_bf16(
    const u16* __restrict__ xin, const int* __restrict__ csr,
    const int* __restrict__ rowstart, const int* __restrict__ deg,
    u16* __restrict__ mout)
{
    int w = (blockIdx.x * blockDim.x + threadIdx.x) >> 6;
    if (w >= N_NODES) return;
    int lane = threadIdx.x & 63;
    int beg = __builtin_amdgcn_readfirstlane(rowstart[w]);
    int d   = __builtin_amdgcn_readfirstlane(deg[w]);
    const u16* base = xin + (lane << 1);    // 2 bf16 (4B) per lane, row=256B

    float ax[8], ay[8];
#pragma unroll
    for (int u = 0; u < 8; ++u) { ax[u] = 0.f; ay[u] = 0.f; }

    int i = 0;
    for (; i + 8 <= d; i += 8) {
        int s[8];
#pragma unroll
        for (int u = 0; u < 8; ++u) s[u] = csr[beg + i + u];
#pragma unroll
        for (int u = 0; u < 8; ++u) {
            u32 v = *(const u32*)(base + ((size_t)s[u] << 7));
            ax[u] += __uint_as_float(v << 16);
            ay[u] += __uint_as_float(v & 0xffff0000u);
        }
    }
    if (i < d) {
        int cnt = d - i;  // 1..7, wave-uniform
        int s[8];
#pragma unroll
        for (int u = 0; u < 8; ++u) s[u] = csr[beg + i + ((u < cnt) ? u : 0)];
#pragma unroll
        for (int u = 0; u < 8; ++u) {
            u32 v = *(const u32*)(base + ((size_t)s[u] << 7));
            if (u < cnt) {
                ax[u] += __uint_as_float(v << 16);
                ay[u] += __uint_as_float(v & 0xffff0000u);
            }
        }
    }

#pragma unroll
    for (int u = 0; u < 4; ++u) { ax[u] += ax[u + 4]; ay[u] += ay[u + 4]; }
    ax[0] += ax[2]; ay[0] += ay[2];
    ax[1] += ax[3]; ay[1] += ay[3];
    ax[0] += ax[1]; ay[0] += ay[1];

    float inv = 1.f / (float)(d > 0 ? d : 1);
    u32 packed = (u32)f2bf(ax[0] * inv) | ((u32)f2bf(ay[0] * inv) << 16);
    *(u32*)(mout + ((size_t)w << 7) + (lane << 1)) = packed;
}

// ---------------- MFMA dual-GEMM v3: pipelined, counted-vmcnt barrier ----------------
// R10 lesson: __syncthreads drains vmcnt(0) per tile -> serial load/compute, MfmaUtil 3%.
// v3: 2-deep register double-buffer (named A/B sets, rule #20) + raw s_barrier with
// s_waitcnt vmcnt(8): the 8 newest (prefetch) loads stay in flight across the barrier,
// while all older ops (this wave's loads of the tile being stored) are provably done.
// In-place invariant: stores of tile T happen only after ALL waves' loads of tile T
// completed -- guaranteed by the explicit vmcnt(8)+barrier regardless of compiler
// scheduling of MFMAs (rule #18). nt is always even (8, or 2 in the last block).
#define GEMM_SYNC() asm volatile("s_waitcnt vmcnt(8)\n\ts_barrier" ::: "memory")

__global__ __launch_bounds__(512, 2) void gemm_mfma3(
    const u16* __restrict__ Ab, const u16* __restrict__ Xb,
    const u16* __restrict__ Wlb, const float* __restrict__ bl,
    const u16* __restrict__ Wrb, void* __restrict__ outp, int relu_bf16)
{
    const int wv = threadIdx.x >> 6;   // 0..7 = output col-tile
    const int l  = threadIdx.x & 63;
    const int lr = l & 15;             // row-in-tile (A) / col-in-tile (B, C/D)
    const int lq = l >> 4;             // 0..3 k-slice / C-row group
    const int r0 = blockIdx.x * 128;
    const int nt = min(8, (N_NODES - r0 + 15) >> 4);   // 8 or 2 (even)

    // B fragments, loaded once: lane l holds W[wv*16+lr][k0*32+lq*8+j]
    const u16* wlb = Wlb + (size_t)(wv * 16 + lr) * H + lq * 8;
    const u16* wrb = Wrb + (size_t)(wv * 16 + lr) * H + lq * 8;
    bf16x8 bwl[4], bwr[4];
#pragma unroll
    for (int k0 = 0; k0 < 4; ++k0) {
        bwl[k0] = *(const bf16x8*)(wlb + k0 * 32);
        bwr[k0] = *(const bf16x8*)(wrb + k0 * 32);
    }
    const int n = wv * 16 + lr;        // output col (C/D: col=lane&15)
    const float bv = bl[n];

    u16* outb = (u16*)outp;
    float* outf = (float*)outp;

    const u16* aL = Ab + lq * 8;
    const u16* xL = Xb + lq * 8;

#define LOADT(dst_a, dst_x, tt)  do {                                   \
        int m_ = r0 + (tt) * 16 + lr;                                   \
        size_t mc_ = (size_t)((m_ < N_NODES) ? m_ : (N_NODES - 1)) * H; \
        _Pragma("unroll")                                               \
        for (int k0 = 0; k0 < 4; ++k0) {                                \
            dst_a[k0] = *(const bf16x8*)(aL + mc_ + k0 * 32);           \
            dst_x[k0] = *(const bf16x8*)(xL + mc_ + k0 * 32);           \
        }                                                               \
    } while (0)

#define MFMAT(src_a, src_x, acc_)  do {                                 \
        _Pragma("unroll")                                               \
        for (int k0 = 0; k0 < 4; ++k0) {                                \
            acc_ = __builtin_amdgcn_mfma_f32_16x16x32_bf16(src_a[k0], bwl[k0], acc_, 0, 0, 0); \
            acc_ = __builtin_amdgcn_mfma_f32_16x16x32_bf16(src_x[k0], bwr[k0], acc_, 0, 0, 0); \
        }                                                               \
    } while (0)

#define STORET(acc_, tt)  do {                                          \
        _Pragma("unroll")                                               \
        for (int r = 0; r < 4; ++r) {                                   \
            int row_ = r0 + (tt) * 16 + lq * 4 + r;                     \
            if (row_ < N_NODES) {                                       \
                float v_ = acc_[r] + bv;                                \
                if (relu_bf16) outb[(size_t)row_ * H + n] = f2bf(fmaxf(v_, 0.f)); \
                else           outf[(size_t)row_ * H + n] = v_;         \
            }                                                           \
        }                                                               \
    } while (0)

    bf16x8 afA[4], xfA[4], afB[4], xfB[4];
    LOADT(afA, xfA, 0);                       // prologue: tile 0 -> A

    for (int t = 0; t < nt; t += 2) {
        LOADT(afB, xfB, t + 1);               // prefetch t+1 -> B (t+1<nt: nt even)
        f32x4 accA = (f32x4)0.f;
        MFMAT(afA, xfA, accA);
        GEMM_SYNC();                          // all waves' tile-t loads done; B in flight
        STORET(accA, t);

        if (t + 2 < nt) LOADT(afA, xfA, t + 2);   // prefetch t+2 -> A (uniform branch)
        f32x4 accB = (f32x4)0.f;
        MFMAT(afB, xfB, accB);
        GEMM_SYNC();                          // all waves' tile-(t+1) loads done
        STORET(accB, t + 1);
    }
#undef LOADT
#undef MFMAT
#undef STORET
}

// ---------------- launch ----------------

extern "C" void kernel_launch(void* const* d_in, const int* in_sizes, int n_in,
                              void* d_out, int out_size, void* d_ws, size_t ws_size,
                              hipStream_t stream) {
    const float* x   = (const float*)d_in[0];
    const int*   ei  = (const int*)d_in[1];
    const float* W1l = (const float*)d_in[2];
    const float* b1l = (const float*)d_in[3];
    const float* W1r = (const float*)d_in[4];
    const float* W2l = (const float*)d_in[5];
    const float* b2l = (const float*)d_in[6];
    const float* W2r = (const float*)d_in[7];

    const int* src = ei;             // edge_index[0]
    const int* dst = ei + N_EDGES;   // edge_index[1]

    // workspace layout (~58.8 MB)
    u16* xb       = (u16*)d_ws;                          // N*H bf16; becomes h1b after gemm1
    u16* mb       = xb + (size_t)N_NODES * H;            // N*H bf16
    int* deg      = (int*)(mb + (size_t)N_NODES * H);    // N
    int* rowstart = deg + N_NODES;                       // N
    int* wslot    = rowstart + N_NODES;                  // N ints (bf16 weights home)
    int* csr      = wslot + N_NODES;                     // E
    int* bsums    = csr + N_EDGES;                       // 128
    int* boffs    = bsums + 128;                         // 128
    int* bcur     = boffs + 128;                         // NB bucket cursors
    u16* Wb       = (u16*)wslot;                         // 4 x 128*128 bf16 = 128KB
    u16* W1lb = Wb;
    u16* W1rb = Wb + 16384;
    u16* W2lb = Wb + 32768;
    u16* W2rb = Wb + 49152;

    const int nb = (N_NODES + 1023) / 1024;  // 98 scan blocks

    // CSR build: histogram -> scan -> 2-pass LDS-staged counting sort
    zero_ints<<<(N_NODES + 255) / 256, 256, 0, stream>>>(deg, N_NODES);
    count_deg<<<(N_EDGES + 255) / 256, 256, 0, stream>>>(dst, deg, N_EDGES);
    scan_blocks<<<nb, 1024, 0, stream>>>(deg, rowstart, bsums, N_NODES);
    scan_sums<<<1, 128, 0, stream>>>(bsums, boffs, nb);
    add_offsets<<<(N_NODES + 255) / 256, 256, 0, stream>>>(rowstart, boffs, N_NODES);
    init_bcur<<<(NB + 255) / 256, 256, 0, stream>>>(rowstart, bcur);
    p1_bin<<<P1_BLOCKS, 1024, 0, stream>>>(src, dst, bcur, (u32*)csr);
    p2_scatter<<<NB, 1024, 0, stream>>>(rowstart, csr);

    // precasts (cast_w reuses the dead cursor slot region)
    cast_w<<<65536 / 256, 256, 0, stream>>>(W1l, W1r, W2l, W2r, Wb);
    cast_x<<<(N_NODES * H / 8) / 256, 256, 0, stream>>>(x, xb);

    const int gemm_grid = (N_NODES + 127) / 128;   // 782

    // layer 1
    agg_bf16<<<(N_NODES + 3) / 4, 256, 0, stream>>>(xb, csr, rowstart, deg, mb);
    gemm_mfma3<<<gemm_grid, 512, 0, stream>>>(mb, xb, W1lb, b1l, W1rb, xb, 1);  // h1b in-place over xb

    // layer 2
    agg_bf16<<<(N_NODES + 3) / 4, 256, 0, stream>>>(xb, csr, rowstart, deg, mb);
    gemm_mfma3<<<gemm_grid, 512, 0, stream>>>(mb, xb, W2lb, b2l, W2rb, d_out, 0);
}

// Round 12
// 298.057 us; speedup vs baseline: 1.2557x; 1.2557x over previous
//
#include <hip/hip_runtime.h>

#define N_NODES 100000
#define N_EDGES 1600000
#define H 128

#define NB 391        // dst buckets of 256 nodes: ceil(100000/256)
#define P1_EPB 4096   // edges per pass-1 block
#define P1_BLOCKS ((N_EDGES + P1_EPB - 1) / P1_EPB)   // 391
#define P2_CAP 6144   // bucket capacity (mean 4096, sigma~64)

typedef unsigned short u16;
typedef unsigned int u32;
typedef short bf16x8 __attribute__((ext_vector_type(8)));
typedef float f32x4 __attribute__((ext_vector_type(4)));

static __device__ __forceinline__ u16 f2bf(float f) {  // RNE float->bf16
    u32 u = __float_as_uint(f);
    u += 0x7fffu + ((u >> 16) & 1u);
    return (u16)(u >> 16);
}

// ---------------- CSR build ----------------

__global__ void zero_ints(int* __restrict__ p, int n) {
    int i = blockIdx.x * blockDim.x + threadIdx.x;
    if (i < n) p[i] = 0;
}

__global__ void count_deg(const int* __restrict__ dst, int* __restrict__ deg, int e) {
    int i = blockIdx.x * blockDim.x + threadIdx.x;
    if (i < e) atomicAdd(&deg[dst[i]], 1);
}

__global__ void scan_blocks(const int* __restrict__ deg, int* __restrict__ rowstart,
                            int* __restrict__ bsums, int n) {
    __shared__ int s[1024];
    int t = threadIdx.x;
    int i = blockIdx.x * 1024 + t;
    int v = (i < n) ? deg[i] : 0;
    s[t] = v;
    __syncthreads();
    for (int off = 1; off < 1024; off <<= 1) {
        int add = (t >= off) ? s[t - off] : 0;
        __syncthreads();
        s[t] += add;
        __syncthreads();
    }
    if (i < n) rowstart[i] = s[t] - v;   // exclusive
    if (t == 1023) bsums[blockIdx.x] = s[t];
}

__global__ void scan_sums(const int* __restrict__ bsums, int* __restrict__ boffs, int nb) {
    __shared__ int s[128];
    int t = threadIdx.x;
    int v = (t < nb) ? bsums[t] : 0;
    s[t] = v;
    __syncthreads();
    for (int off = 1; off < 128; off <<= 1) {
        int add = (t >= off) ? s[t - off] : 0;
        __syncthreads();
        s[t] += add;
        __syncthreads();
    }
    if (t < nb) boffs[t] = s[t] - v;     // exclusive
}

__global__ void add_offsets(int* __restrict__ rowstart, const int* __restrict__ boffs, int n) {
    int i = blockIdx.x * blockDim.x + threadIdx.x;
    if (i < n) rowstart[i] += boffs[i >> 10];
}

__global__ void init_bcur(const int* __restrict__ rowstart, int* __restrict__ bcur) {
    int b = blockIdx.x * 256 + threadIdx.x;
    if (b < NB) bcur[b] = rowstart[b << 8];
}

// Pass 1: bin edges by dst>>8 into bucket-contiguous csr ranges (packed u32:
// bits[24:17]=dst&255, bits[16:0]=src). LDS-staged so global writes are
// slot-ordered bucket runs (R6/R7 lesson: raw 4B scatter = 64B partial-line
// HBM writebacks; XCD L2s can't merge).
__global__ __launch_bounds__(1024) void p1_bin(
    const int* __restrict__ src, const int* __restrict__ dst,
    int* __restrict__ bcur, u32* __restrict__ csrp)
{
    __shared__ int s_cnt[NB];      // histogram, then running local cursor
    __shared__ int s_lstart[NB];   // block-local exclusive start per bucket
    __shared__ int s_gbase[NB];    // reserved global base per bucket
    __shared__ int s_scan[512];
    __shared__ u32 s_val[P1_EPB];
    __shared__ u32 s_gaddr[P1_EPB];

    const int t = threadIdx.x;
    const int e0 = blockIdx.x * P1_EPB;
    const int ecnt = min(P1_EPB, N_EDGES - e0);

    for (int i = t; i < NB; i += 1024) s_cnt[i] = 0;
    __syncthreads();
    for (int i = t; i < ecnt; i += 1024)
        atomicAdd(&s_cnt[dst[e0 + i] >> 8], 1);
    __syncthreads();

    int v = (t < NB) ? s_cnt[t] : 0;
    if (t < 512) s_scan[t] = v;
    __syncthreads();
    for (int off = 1; off < 512; off <<= 1) {
        int add = (t < 512 && t >= off) ? s_scan[t - off] : 0;
        __syncthreads();
        if (t < 512) s_scan[t] += add;
        __syncthreads();
    }
    if (t < NB) {
        int ls = s_scan[t] - v;   // exclusive
        s_lstart[t] = ls;
        s_gbase[t] = (v > 0) ? atomicAdd(&bcur[t], v) : 0;
        s_cnt[t] = ls;            // becomes running cursor
    }
    __syncthreads();

    for (int i = t; i < ecnt; i += 1024) {
        int d = dst[e0 + i];
        int s = src[e0 + i];
        int b = d >> 8;
        int slot = atomicAdd(&s_cnt[b], 1);
        s_val[slot]   = ((u32)(d & 255) << 17) | (u32)s;
        s_gaddr[slot] = (u32)(s_gbase[b] + (slot - s_lstart[b]));
    }
    __syncthreads();
    for (int i = t; i < ecnt; i += 1024)
        csrp[s_gaddr[i]] = s_val[i];
}

// Pass 2: one block per bucket; bin packed entries to exact per-node order in
// LDS, write back fully coalesced. In-place safe (load barrier store).
__global__ __launch_bounds__(1024) void p2_scatter(
    const int* __restrict__ rowstart, int* __restrict__ csr)
{
    __shared__ int s_cur[256];
    __shared__ u32 s_out[P2_CAP];
    const int b = blockIdx.x;
    const int t = threadIdx.x;
    const int n0 = b << 8;
    const int s0 = rowstart[n0];
    const int s1 = (b == NB - 1) ? N_EDGES : rowstart[n0 + 256];
    const int cnt = s1 - s0;

    if (t < 256) {
        int node = n0 + t;
        s_cur[t] = (node < N_NODES) ? (rowstart[node] - s0) : cnt;
    }
    __syncthreads();
    for (int i = t; i < cnt; i += 1024) {
        u32 p = (u32)csr[s0 + i];
        int pos = atomicAdd(&s_cur[p >> 17], 1);
        s_out[pos] = p & 0x1FFFFu;
    }
    __syncthreads();
    for (int i = t; i < cnt; i += 1024)
        csr[s0 + i] = (int)s_out[i];
}

// ---------------- casts ----------------

__global__ __launch_bounds__(256) void cast_x(const float* __restrict__ in,
                                              u16* __restrict__ out) {
    int i = blockIdx.x * 256 + threadIdx.x;   // 1.6M threads x 8 elems
    const float4 v0 = *(const float4*)(in + (size_t)i * 8);
    const float4 v1 = *(const float4*)(in + (size_t)i * 8 + 4);
    u16 o[8];
    o[0]=f2bf(v0.x); o[1]=f2bf(v0.y); o[2]=f2bf(v0.z); o[3]=f2bf(v0.w);
    o[4]=f2bf(v1.x); o[5]=f2bf(v1.y); o[6]=f2bf(v1.z); o[7]=f2bf(v1.w);
    *(bf16x8*)(out + (size_t)i * 8) = *(bf16x8*)o;
}

__global__ __launch_bounds__(256) void cast_w(const float* __restrict__ w1l,
                                              const float* __restrict__ w1r,
                                              const float* __restrict__ w2l,
                                              const float* __restrict__ w2r,
                                              u16* __restrict__ out) {
    int i = blockIdx.x * 256 + threadIdx.x;   // 65536 threads
    int mat = i >> 14, idx = i & 16383;
    const float* s = (mat == 0) ? w1l : (mat == 1) ? w1r : (mat == 2) ? w2l : w2r;
    out[i] = f2bf(s[idx]);
}

// ---------------- Aggregation: wave/node, 8-wide MLP, bf16 in/out ----------------

__global__ __launch_bounds__(256) void agg_bf16(
    const u16* __restrict__ xin, const int* __restrict__ csr,
    const int* __restrict__ rowstart, const int* __restrict__ deg,
    u16* __restrict__ mout)
{
    int w = (blockIdx.x * blockDim.x + threadIdx.x) >> 6;
    if (w >= N_NODES) return;
    int lane = threadIdx.x & 63;
    int beg = __builtin_amdgcn_readfirstlane(rowstart[w]);
    int d   = __builtin_amdgcn_readfirstlane(deg[w]);
    const u16* base = xin + (lane << 1);    // 2 bf16 (4B) per lane, row=256B

    float ax[8], ay[8];
#pragma unroll
    for (int u = 0; u < 8; ++u) { ax[u] = 0.f; ay[u] = 0.f; }

    int i = 0;
    for (; i + 8 <= d; i += 8) {
        int s[8];
#pragma unroll
        for (int u = 0; u < 8; ++u) s[u] = csr[beg + i + u];
#pragma unroll
        for (int u = 0; u < 8; ++u) {
            u32 v = *(const u32*)(base + ((size_t)s[u] << 7));
            ax[u] += __uint_as_float(v << 16);
            ay[u] += __uint_as_float(v & 0xffff0000u);
        }
    }
    if (i < d) {
        int cnt = d - i;  // 1..7, wave-uniform
        int s[8];
#pragma unroll
        for (int u = 0; u < 8; ++u) s[u] = csr[beg + i + ((u < cnt) ? u : 0)];
#pragma unroll
        for (int u = 0; u < 8; ++u) {
            u32 v = *(const u32*)(base + ((size_t)s[u] << 7));
            if (u < cnt) {
                ax[u] += __uint_as_float(v << 16);
                ay[u] += __uint_as_float(v & 0xffff0000u);
            }
        }
    }

#pragma unroll
    for (int u = 0; u < 4; ++u) { ax[u] += ax[u + 4]; ay[u] += ay[u + 4]; }
    ax[0] += ax[2]; ay[0] += ay[2];
    ax[1] += ax[3]; ay[1] += ay[3];
    ax[0] += ax[1]; ay[0] += ay[1];

    float inv = 1.f / (float)(d > 0 ? d : 1);
    u32 packed = (u32)f2bf(ax[0] * inv) | ((u32)f2bf(ay[0] * inv) << 16);
    *(u32*)(mout + ((size_t)w << 7) + (lane << 1)) = packed;
}

// ---------------- MFMA dual-GEMM v4: LDS bulk-stage + 1 barrier + coalesced out ----------------
// R10/R11 lesson: per-tile barriers with register pipelining stayed latency-bound
// (MfmaUtil 3%, ~1 TB/s): ~40 MFMA-cycles per tile can't hide ~300-900-cycle memory,
// and every sync waited on 32B-chunk scatter stores (2x write amplification).
// v4 = canonical Section-5 shape, minimal: block=256thr/4 waves, 128-row tile.
//   1) bulk-stage A(32KB)+X(32KB) via global_load_lds w=16 (all in flight, ONE drain)
//   2) weights in regs (wave owns 32 cols; 16 bf16x8 loaded once, L2-hot)
//   3) 8 row-tiles x 2 col-tiles, acc in regs (static idx), 128 MFMAs/wave
//   4) epilogue: acc -> LDS (A/X dead; fp32 tile = exactly 64KB), barrier,
//      flush 16B/thread coalesced -> full-line HBM writes (kills 2x amplification)
// In-place (layer1 out==X): block reads only its own 128 rows, staged before any
// store (syncthreads drains staging vmcnt); other blocks touch disjoint rows.
__global__ __launch_bounds__(256) void gemm_mfma4(
    const u16* __restrict__ Ab, const u16* __restrict__ Xb,
    const u16* __restrict__ Wlb, const float* __restrict__ bl,
    const u16* __restrict__ Wrb, void* __restrict__ outp, int relu_bf16)
{
    __shared__ u16 lds[32768];          // 64KB: A[0,16384), X[16384,32768) u16 idx
    const int t  = threadIdx.x;
    const int wv = t >> 6;              // 0..3
    const int l  = t & 63;
    const int lr = l & 15;              // A-row / B-col / D-col in 16-tile
    const int lq = l >> 4;              // 0..3 k-slice / D-row group
    const int r0 = blockIdx.x * 128;

    // ---- weights: wave wv owns output cols [wv*32, wv*32+32) ----
    bf16x8 bwl[2][4], bwr[2][4];
#pragma unroll
    for (int ct = 0; ct < 2; ++ct) {
        const u16* wl = Wlb + (size_t)(wv * 32 + ct * 16 + lr) * H + lq * 8;
        const u16* wr = Wrb + (size_t)(wv * 32 + ct * 16 + lr) * H + lq * 8;
#pragma unroll
        for (int k0 = 0; k0 < 4; ++k0) {
            bwl[ct][k0] = *(const bf16x8*)(wl + k0 * 32);
            bwr[ct][k0] = *(const bf16x8*)(wr + k0 * 32);
        }
    }
    float bv[2] = { bl[wv * 32 + lr], bl[wv * 32 + 16 + lr] };

    // ---- bulk stage: each wave 8KB of A + 8KB of X, 1KB per inst ----
    const char* ag = (const char*)(Ab + (size_t)r0 * H);
    const char* xg = (const char*)(Xb + (size_t)r0 * H);
#pragma unroll
    for (int c = 0; c < 8; ++c) {
        int boff = wv * 8192 + c * 1024;          // wave-uniform byte offset
        __builtin_amdgcn_global_load_lds(
            (const u32*)(ag + boff + (l << 4)), (u32*)&lds[boff >> 1], 16, 0, 0);
        __builtin_amdgcn_global_load_lds(
            (const u32*)(xg + boff + (l << 4)), (u32*)&lds[(32768 + boff) >> 1], 16, 0, 0);
    }
    __syncthreads();   // drains staging vmcnt; tile visible to all waves

    // ---- compute: acc[rt][ct] fully in regs, static indexing ----
    f32x4 acc[8][2];
#pragma unroll
    for (int rt = 0; rt < 8; ++rt) {
        bf16x8 af[4], xf[4];
#pragma unroll
        for (int k0 = 0; k0 < 4; ++k0) {
            int idx = (rt * 16 + lr) * 128 + k0 * 32 + lq * 8;
            af[k0] = *(const bf16x8*)&lds[idx];
            xf[k0] = *(const bf16x8*)&lds[16384 + idx];
        }
#pragma unroll
        for (int ct = 0; ct < 2; ++ct) {
            f32x4 a = (f32x4)0.f;
#pragma unroll
            for (int k0 = 0; k0 < 4; ++k0) {
                a = __builtin_amdgcn_mfma_f32_16x16x32_bf16(af[k0], bwl[ct][k0], a, 0, 0, 0);
                a = __builtin_amdgcn_mfma_f32_16x16x32_bf16(xf[k0], bwr[ct][k0], a, 0, 0, 0);
            }
            acc[rt][ct] = a;
        }
    }
    __syncthreads();   // all LDS reads done; buffer reusable for out-tile

    // ---- epilogue: tile -> LDS, barrier, coalesced flush ----
    if (relu_bf16) {
        // bf16 out tile: 128x128 u16 = 32KB
#pragma unroll
        for (int rt = 0; rt < 8; ++rt)
#pragma unroll
        for (int ct = 0; ct < 2; ++ct)
#pragma unroll
        for (int r = 0; r < 4; ++r)
            lds[(rt * 16 + lq * 4 + r) * 128 + wv * 32 + ct * 16 + lr] =
                f2bf(fmaxf(acc[rt][ct][r] + bv[ct], 0.f));
        __syncthreads();
        u16* ob = (u16*)outp;
#pragma unroll
        for (int c = 0; c < 8; ++c) {
            int eoff = c * 2048 + t * 8;          // u16 elements
            int row = r0 + (eoff >> 7);
            if (row < N_NODES)
                *(bf16x8*)(ob + (size_t)r0 * H + eoff) = *(const bf16x8*)&lds[eoff];
        }
    } else {
        // fp32 out tile: 128x128 f32 = 64KB (exactly the A/X buffer)
        float* of = (float*)lds;
#pragma unroll
        for (int rt = 0; rt < 8; ++rt)
#pragma unroll
        for (int ct = 0; ct < 2; ++ct)
#pragma unroll
        for (int r = 0; r < 4; ++r)
            of[(rt * 16 + lq * 4 + r) * 128 + wv * 32 + ct * 16 + lr] =
                acc[rt][ct][r] + bv[ct];
        __syncthreads();
        float* og = (float*)outp;
#pragma unroll
        for (int c = 0; c < 16; ++c) {
            int eoff = c * 1024 + t * 4;          // f32 elements
            int row = r0 + (eoff >> 7);
            if (row < N_NODES)
                *(float4*)(og + (size_t)r0 * H + eoff) = *(const float4*)&of[eoff];
        }
    }
}

// ---------------- launch ----------------

extern "C" void kernel_launch(void* const* d_in, const int* in_sizes, int n_in,
                              void* d_out, int out_size, void* d_ws, size_t ws_size,
                              hipStream_t stream) {
    const float* x   = (const float*)d_in[0];
    const int*   ei  = (const int*)d_in[1];
    const float* W1l = (const float*)d_in[2];
    const float* b1l = (const float*)d_in[3];
    const float* W1r = (const float*)d_in[4];
    const float* W2l = (const float*)d_in[5];
    const float* b2l = (const float*)d_in[6];
    const float* W2r = (const float*)d_in[7];

    const int* src = ei;             // edge_index[0]
    const int* dst = ei + N_EDGES;   // edge_index[1]

    // workspace layout (~58.8 MB)
    u16* xb       = (u16*)d_ws;                          // N*H bf16; becomes h1b after gemm1
    u16* mb       = xb + (size_t)N_NODES * H;            // N*H bf16
    int* deg      = (int*)(mb + (size_t)N_NODES * H);    // N
    int* rowstart = deg + N_NODES;                       // N
    int* wslot    = rowstart + N_NODES;                  // N ints (bf16 weights home)
    int* csr      = wslot + N_NODES;                     // E
    int* bsums    = csr + N_EDGES;                       // 128
    int* boffs    = bsums + 128;                         // 128
    int* bcur     = boffs + 128;                         // NB bucket cursors
    u16* Wb       = (u16*)wslot;                         // 4 x 128*128 bf16 = 128KB
    u16* W1lb = Wb;
    u16* W1rb = Wb + 16384;
    u16* W2lb = Wb + 32768;
    u16* W2rb = Wb + 49152;

    const int nb = (N_NODES + 1023) / 1024;  // 98 scan blocks

    // CSR build: histogram -> scan -> 2-pass LDS-staged counting sort
    zero_ints<<<(N_NODES + 255) / 256, 256, 0, stream>>>(deg, N_NODES);
    count_deg<<<(N_EDGES + 255) / 256, 256, 0, stream>>>(dst, deg, N_EDGES);
    scan_blocks<<<nb, 1024, 0, stream>>>(deg, rowstart, bsums, N_NODES);
    scan_sums<<<1, 128, 0, stream>>>(bsums, boffs, nb);
    add_offsets<<<(N_NODES + 255) / 256, 256, 0, stream>>>(rowstart, boffs, N_NODES);
    init_bcur<<<(NB + 255) / 256, 256, 0, stream>>>(rowstart, bcur);
    p1_bin<<<P1_BLOCKS, 1024, 0, stream>>>(src, dst, bcur, (u32*)csr);
    p2_scatter<<<NB, 1024, 0, stream>>>(rowstart, csr);

    // precasts (cast_w reuses the dead cursor slot region)
    cast_w<<<65536 / 256, 256, 0, stream>>>(W1l, W1r, W2l, W2r, Wb);
    cast_x<<<(N_NODES * H / 8) / 256, 256, 0, stream>>>(x, xb);

    const int gemm_grid = (N_NODES + 127) / 128;   // 782

    // layer 1
    agg_bf16<<<(N_NODES + 3) / 4, 256, 0, stream>>>(xb, csr, rowstart, deg, mb);
    gemm_mfma4<<<gemm_grid, 256, 0, stream>>>(mb, xb, W1lb, b1l, W1rb, xb, 1);  // h1b in-place over xb

    // layer 2
    agg_bf16<<<(N_NODES + 3) / 4, 256, 0, stream>>>(xb, csr, rowstart, deg, mb);
    gemm_mfma4<<<gemm_grid, 256, 0, stream>>>(mb, xb, W2lb, b2l, W2rb, d_out, 0);
}

// Round 13
// 239.903 us; speedup vs baseline: 1.5601x; 1.2424x over previous
//
#include <hip/hip_runtime.h>

#define N_NODES 100000
#define N_EDGES 1600000
#define H 128

#define NB 391        // dst buckets of 256 nodes: ceil(100000/256)
#define P1_EPB 4096   // edges per pass-1/bucket-count block
#define P1_BLOCKS ((N_EDGES + P1_EPB - 1) / P1_EPB)   // 391
#define P2_CAP 6144   // bucket capacity (mean 4096, sigma~64)

typedef unsigned short u16;
typedef unsigned int u32;
typedef short bf16x8 __attribute__((ext_vector_type(8)));
typedef float f32x4 __attribute__((ext_vector_type(4)));

static __device__ __forceinline__ u16 f2bf(float f) {  // RNE float->bf16
    u32 u = __float_as_uint(f);
    u += 0x7fffu + ((u >> 16) & 1u);
    return (u16)(u >> 16);
}

// ---------------- CSR build ----------------
// R12 lesson (count_deg): 1.6M random global atomics onto 100K counters cost
// 49.9MB WRITE_SIZE (125x amplification) / 66us -- same partial-line-writeback
// disease as R6's fill_csr. All per-node counting now happens in LDS inside
// the bucketed counting sort; global histogram atomics are per-BUCKET only.

__global__ void zero_ints(int* __restrict__ p, int n) {
    int i = blockIdx.x * blockDim.x + threadIdx.x;
    if (i < n) p[i] = 0;
}

// per-block LDS histogram of dst>>8; one global atomicAdd per bucket per block
__global__ __launch_bounds__(1024) void bucket_count(
    const int* __restrict__ dst, int* __restrict__ gcount)
{
    __shared__ int s_cnt[NB];
    const int t = threadIdx.x;
    const int e0 = blockIdx.x * P1_EPB;
    const int ecnt = min(P1_EPB, N_EDGES - e0);
    for (int i = t; i < NB; i += 1024) s_cnt[i] = 0;
    __syncthreads();
    for (int i = t; i < ecnt; i += 1024)
        atomicAdd(&s_cnt[dst[e0 + i] >> 8], 1);
    __syncthreads();
    for (int i = t; i < NB; i += 1024)
        if (s_cnt[i] > 0) atomicAdd(&gcount[i], s_cnt[i]);
}

// single block: scan 391 bucket totals -> bstart (exclusive, +sentinel), bcur
__global__ __launch_bounds__(512) void bucket_scan(
    const int* __restrict__ gcount, int* __restrict__ bstart, int* __restrict__ bcur)
{
    __shared__ int s[512];
    int t = threadIdx.x;
    int v = (t < NB) ? gcount[t] : 0;
    s[t] = v;
    __syncthreads();
    for (int off = 1; off < 512; off <<= 1) {
        int add = (t >= off) ? s[t - off] : 0;
        __syncthreads();
        s[t] += add;
        __syncthreads();
    }
    if (t < NB) {
        int excl = s[t] - v;
        bstart[t] = excl;
        bcur[t] = excl;
    }
    if (t == NB - 1) bstart[NB] = s[t];   // == N_EDGES
}

// Pass 1: bin edges by dst>>8 into bucket-contiguous csr ranges (packed u32:
// bits[24:17]=dst&255, bits[16:0]=src). LDS-staged so global writes are
// slot-ordered bucket runs.
__global__ __launch_bounds__(1024) void p1_bin(
    const int* __restrict__ src, const int* __restrict__ dst,
    int* __restrict__ bcur, u32* __restrict__ csrp)
{
    __shared__ int s_cnt[NB];      // histogram, then running local cursor
    __shared__ int s_lstart[NB];   // block-local exclusive start per bucket
    __shared__ int s_gbase[NB];    // reserved global base per bucket
    __shared__ int s_scan[512];
    __shared__ u32 s_val[P1_EPB];
    __shared__ u32 s_gaddr[P1_EPB];

    const int t = threadIdx.x;
    const int e0 = blockIdx.x * P1_EPB;
    const int ecnt = min(P1_EPB, N_EDGES - e0);

    for (int i = t; i < NB; i += 1024) s_cnt[i] = 0;
    __syncthreads();
    for (int i = t; i < ecnt; i += 1024)
        atomicAdd(&s_cnt[dst[e0 + i] >> 8], 1);
    __syncthreads();

    int v = (t < NB) ? s_cnt[t] : 0;
    if (t < 512) s_scan[t] = v;
    __syncthreads();
    for (int off = 1; off < 512; off <<= 1) {
        int add = (t < 512 && t >= off) ? s_scan[t - off] : 0;
        __syncthreads();
        if (t < 512) s_scan[t] += add;
        __syncthreads();
    }
    if (t < NB) {
        int ls = s_scan[t] - v;   // exclusive
        s_lstart[t] = ls;
        s_gbase[t] = (v > 0) ? atomicAdd(&bcur[t], v) : 0;
        s_cnt[t] = ls;            // becomes running cursor
    }
    __syncthreads();

    for (int i = t; i < ecnt; i += 1024) {
        int d = dst[e0 + i];
        int s = src[e0 + i];
        int b = d >> 8;
        int slot = atomicAdd(&s_cnt[b], 1);
        s_val[slot]   = ((u32)(d & 255) << 17) | (u32)s;
        s_gaddr[slot] = (u32)(s_gbase[b] + (slot - s_lstart[b]));
    }
    __syncthreads();
    for (int i = t; i < ecnt; i += 1024)
        csrp[s_gaddr[i]] = s_val[i];
}

// Pass 2: one block per bucket. LDS-histogram the 256 dst-lows -> LDS scan ->
// deg/rowstart written COALESCED (256 consecutive ints/block); then in-LDS
// node-order scatter + coalesced csr writeback.
__global__ __launch_bounds__(1024) void p2_scatter(
    const int* __restrict__ bstart, int* __restrict__ rowstart,
    int* __restrict__ deg, int* __restrict__ csr)
{
    __shared__ u32 s_in[P2_CAP];
    __shared__ u32 s_out[P2_CAP];
    __shared__ int s_cnt[256];
    __shared__ int s_loc[256];
    const int b = blockIdx.x;
    const int t = threadIdx.x;
    const int n0 = b << 8;
    const int s0 = bstart[b];
    const int s1 = bstart[b + 1];
    const int cnt = s1 - s0;

    if (t < 256) s_cnt[t] = 0;
    __syncthreads();
    for (int i = t; i < cnt; i += 1024) {
        u32 p = (u32)csr[s0 + i];
        s_in[i] = p;
        atomicAdd(&s_cnt[p >> 17], 1);
    }
    __syncthreads();
    if (t < 256) s_loc[t] = s_cnt[t];
    __syncthreads();
    for (int off = 1; off < 256; off <<= 1) {
        int add = (t < 256 && t >= off) ? s_loc[t - off] : 0;
        __syncthreads();
        if (t < 256) s_loc[t] += add;
        __syncthreads();
    }
    if (t < 256) {
        int node = n0 + t;
        int excl = s_loc[t] - s_cnt[t];
        if (node < N_NODES) {
            rowstart[node] = s0 + excl;   // coalesced
            deg[node]      = s_cnt[t];    // coalesced
        }
        s_loc[t] = excl;                  // running cursor
    }
    __syncthreads();
    for (int i = t; i < cnt; i += 1024) {
        u32 p = s_in[i];
        int pos = atomicAdd(&s_loc[p >> 17], 1);
        s_out[pos] = p & 0x1FFFFu;
    }
    __syncthreads();
    for (int i = t; i < cnt; i += 1024)
        csr[s0 + i] = (int)s_out[i];
}

// ---------------- casts ----------------

__global__ __launch_bounds__(256) void cast_x(const float* __restrict__ in,
                                              u16* __restrict__ out) {
    int i = blockIdx.x * 256 + threadIdx.x;   // 1.6M threads x 8 elems
    const float4 v0 = *(const float4*)(in + (size_t)i * 8);
    const float4 v1 = *(const float4*)(in + (size_t)i * 8 + 4);
    u16 o[8];
    o[0]=f2bf(v0.x); o[1]=f2bf(v0.y); o[2]=f2bf(v0.z); o[3]=f2bf(v0.w);
    o[4]=f2bf(v1.x); o[5]=f2bf(v1.y); o[6]=f2bf(v1.z); o[7]=f2bf(v1.w);
    *(bf16x8*)(out + (size_t)i * 8) = *(bf16x8*)o;
}

__global__ __launch_bounds__(256) void cast_w(const float* __restrict__ w1l,
                                              const float* __restrict__ w1r,
                                              const float* __restrict__ w2l,
                                              const float* __restrict__ w2r,
                                              u16* __restrict__ out) {
    int i = blockIdx.x * 256 + threadIdx.x;   // 65536 threads
    int mat = i >> 14, idx = i & 16383;
    const float* s = (mat == 0) ? w1l : (mat == 1) ? w1r : (mat == 2) ? w2l : w2r;
    out[i] = f2bf(s[idx]);
}

// ---------------- Aggregation: wave/node, 8-wide MLP, bf16 in/out ----------------

__global__ __launch_bounds__(256) void agg_bf16(
    const u16* __restrict__ xin, const int* __restrict__ csr,
    const int* __restrict__ rowstart, const int* __restrict__ deg,
    u16* __restrict__ mout)
{
    int w = (blockIdx.x * blockDim.x + threadIdx.x) >> 6;
    if (w >= N_NODES) return;
    int lane = threadIdx.x & 63;
    int beg = __builtin_amdgcn_readfirstlane(rowstart[w]);
    int d   = __builtin_amdgcn_readfirstlane(deg[w]);
    const u16* base = xin + (lane << 1);    // 2 bf16 (4B) per lane, row=256B

    float ax[8], ay[8];
#pragma unroll
    for (int u = 0; u < 8; ++u) { ax[u] = 0.f; ay[u] = 0.f; }

    int i = 0;
    for (; i + 8 <= d; i += 8) {
        int s[8];
#pragma unroll
        for (int u = 0; u < 8; ++u) s[u] = csr[beg + i + u];
#pragma unroll
        for (int u = 0; u < 8; ++u) {
            u32 v = *(const u32*)(base + ((size_t)s[u] << 7));
            ax[u] += __uint_as_float(v << 16);
            ay[u] += __uint_as_float(v & 0xffff0000u);
        }
    }
    if (i < d) {
        int cnt = d - i;  // 1..7, wave-uniform
        int s[8];
#pragma unroll
        for (int u = 0; u < 8; ++u) s[u] = csr[beg + i + ((u < cnt) ? u : 0)];
#pragma unroll
        for (int u = 0; u < 8; ++u) {
            u32 v = *(const u32*)(base + ((size_t)s[u] << 7));
            if (u < cnt) {
                ax[u] += __uint_as_float(v << 16);
                ay[u] += __uint_as_float(v & 0xffff0000u);
            }
        }
    }

#pragma unroll
    for (int u = 0; u < 4; ++u) { ax[u] += ax[u + 4]; ay[u] += ay[u + 4]; }
    ax[0] += ax[2]; ay[0] += ay[2];
    ax[1] += ax[3]; ay[1] += ay[3];
    ax[0] += ax[1]; ay[0] += ay[1];

    float inv = 1.f / (float)(d > 0 ? d : 1);
    u32 packed = (u32)f2bf(ax[0] * inv) | ((u32)f2bf(ay[0] * inv) << 16);
    *(u32*)(mout + ((size_t)w << 7) + (lane << 1)) = packed;
}

// ---------------- MFMA dual-GEMM v4: LDS bulk-stage + 1 barrier + coalesced out ----------------
__global__ __launch_bounds__(256) void gemm_mfma4(
    const u16* __restrict__ Ab, const u16* __restrict__ Xb,
    const u16* __restrict__ Wlb, const float* __restrict__ bl,
    const u16* __restrict__ Wrb, void* __restrict__ outp, int relu_bf16)
{
    __shared__ u16 lds[32768];          // 64KB: A[0,16384), X[16384,32768) u16 idx
    const int t  = threadIdx.x;
    const int wv = t >> 6;              // 0..3
    const int l  = t & 63;
    const int lr = l & 15;              // A-row / B-col / D-col in 16-tile
    const int lq = l >> 4;              // 0..3 k-slice / D-row group
    const int r0 = blockIdx.x * 128;

    // ---- weights: wave wv owns output cols [wv*32, wv*32+32) ----
    bf16x8 bwl[2][4], bwr[2][4];
#pragma unroll
    for (int ct = 0; ct < 2; ++ct) {
        const u16* wl = Wlb + (size_t)(wv * 32 + ct * 16 + lr) * H + lq * 8;
        const u16* wr = Wrb + (size_t)(wv * 32 + ct * 16 + lr) * H + lq * 8;
#pragma unroll
        for (int k0 = 0; k0 < 4; ++k0) {
            bwl[ct][k0] = *(const bf16x8*)(wl + k0 * 32);
            bwr[ct][k0] = *(const bf16x8*)(wr + k0 * 32);
        }
    }
    float bv[2] = { bl[wv * 32 + lr], bl[wv * 32 + 16 + lr] };

    // ---- bulk stage: each wave 8KB of A + 8KB of X, 1KB per inst ----
    const char* ag = (const char*)(Ab + (size_t)r0 * H);
    const char* xg = (const char*)(Xb + (size_t)r0 * H);
#pragma unroll
    for (int c = 0; c < 8; ++c) {
        int boff = wv * 8192 + c * 1024;          // wave-uniform byte offset
        __builtin_amdgcn_global_load_lds(
            (const u32*)(ag + boff + (l << 4)), (u32*)&lds[boff >> 1], 16, 0, 0);
        __builtin_amdgcn_global_load_lds(
            (const u32*)(xg + boff + (l << 4)), (u32*)&lds[(32768 + boff) >> 1], 16, 0, 0);
    }
    __syncthreads();   // drains staging vmcnt; tile visible to all waves

    // ---- compute: acc[rt][ct] fully in regs, static indexing ----
    f32x4 acc[8][2];
#pragma unroll
    for (int rt = 0; rt < 8; ++rt) {
        bf16x8 af[4], xf[4];
#pragma unroll
        for (int k0 = 0; k0 < 4; ++k0) {
            int idx = (rt * 16 + lr) * 128 + k0 * 32 + lq * 8;
            af[k0] = *(const bf16x8*)&lds[idx];
            xf[k0] = *(const bf16x8*)&lds[16384 + idx];
        }
#pragma unroll
        for (int ct = 0; ct < 2; ++ct) {
            f32x4 a = (f32x4)0.f;
#pragma unroll
            for (int k0 = 0; k0 < 4; ++k0) {
                a = __builtin_amdgcn_mfma_f32_16x16x32_bf16(af[k0], bwl[ct][k0], a, 0, 0, 0);
                a = __builtin_amdgcn_mfma_f32_16x16x32_bf16(xf[k0], bwr[ct][k0], a, 0, 0, 0);
            }
            acc[rt][ct] = a;
        }
    }
    __syncthreads();   // all LDS reads done; buffer reusable for out-tile

    // ---- epilogue: tile -> LDS, barrier, coalesced flush ----
    if (relu_bf16) {
#pragma unroll
        for (int rt = 0; rt < 8; ++rt)
#pragma unroll
        for (int ct = 0; ct < 2; ++ct)
#pragma unroll
        for (int r = 0; r < 4; ++r)
            lds[(rt * 16 + lq * 4 + r) * 128 + wv * 32 + ct * 16 + lr] =
                f2bf(fmaxf(acc[rt][ct][r] + bv[ct], 0.f));
        __syncthreads();
        u16* ob = (u16*)outp;
#pragma unroll
        for (int c = 0; c < 8; ++c) {
            int eoff = c * 2048 + t * 8;          // u16 elements
            int row = r0 + (eoff >> 7);
            if (row < N_NODES)
                *(bf16x8*)(ob + (size_t)r0 * H + eoff) = *(const bf16x8*)&lds[eoff];
        }
    } else {
        float* of = (float*)lds;
#pragma unroll
        for (int rt = 0; rt < 8; ++rt)
#pragma unroll
        for (int ct = 0; ct < 2; ++ct)
#pragma unroll
        for (int r = 0; r < 4; ++r)
            of[(rt * 16 + lq * 4 + r) * 128 + wv * 32 + ct * 16 + lr] =
                acc[rt][ct][r] + bv[ct];
        __syncthreads();
        float* og = (float*)outp;
#pragma unroll
        for (int c = 0; c < 16; ++c) {
            int eoff = c * 1024 + t * 4;          // f32 elements
            int row = r0 + (eoff >> 7);
            if (row < N_NODES)
                *(float4*)(og + (size_t)r0 * H + eoff) = *(const float4*)&of[eoff];
        }
    }
}

// ---------------- launch ----------------

extern "C" void kernel_launch(void* const* d_in, const int* in_sizes, int n_in,
                              void* d_out, int out_size, void* d_ws, size_t ws_size,
                              hipStream_t stream) {
    const float* x   = (const float*)d_in[0];
    const int*   ei  = (const int*)d_in[1];
    const float* W1l = (const float*)d_in[2];
    const float* b1l = (const float*)d_in[3];
    const float* W1r = (const float*)d_in[4];
    const float* W2l = (const float*)d_in[5];
    const float* b2l = (const float*)d_in[6];
    const float* W2r = (const float*)d_in[7];

    const int* src = ei;             // edge_index[0]
    const int* dst = ei + N_EDGES;   // edge_index[1]

    // workspace layout (~58.8 MB)
    u16* xb       = (u16*)d_ws;                          // N*H bf16; becomes h1b after gemm1
    u16* mb       = xb + (size_t)N_NODES * H;            // N*H bf16
    int* deg      = (int*)(mb + (size_t)N_NODES * H);    // N
    int* rowstart = deg + N_NODES;                       // N
    int* wslot    = rowstart + N_NODES;                  // N ints (bf16 weights home)
    int* csr      = wslot + N_NODES;                     // E
    int* gcount   = csr + N_EDGES;                       // NB
    int* bstart   = gcount + NB;                         // NB+1
    int* bcur     = bstart + NB + 1;                     // NB
    u16* Wb       = (u16*)wslot;                         // 4 x 128*128 bf16 = 128KB
    u16* W1lb = Wb;
    u16* W1rb = Wb + 16384;
    u16* W2lb = Wb + 32768;
    u16* W2rb = Wb + 49152;

    // CSR build: bucket histogram -> bucket scan -> 2-pass LDS counting sort
    // (deg/rowstart emerge coalesced from p2; no per-node global atomics anywhere)
    zero_ints<<<(NB + 255) / 256, 256, 0, stream>>>(gcount, NB);
    bucket_count<<<P1_BLOCKS, 1024, 0, stream>>>(dst, gcount);
    bucket_scan<<<1, 512, 0, stream>>>(gcount, bstart, bcur);
    p1_bin<<<P1_BLOCKS, 1024, 0, stream>>>(src, dst, bcur, (u32*)csr);
    p2_scatter<<<NB, 1024, 0, stream>>>(bstart, rowstart, deg, csr);

    // precasts
    cast_w<<<65536 / 256, 256, 0, stream>>>(W1l, W1r, W2l, W2r, Wb);
    cast_x<<<(N_NODES * H / 8) / 256, 256, 0, stream>>>(x, xb);

    const int gemm_grid = (N_NODES + 127) / 128;   // 782

    // layer 1
    agg_bf16<<<(N_NODES + 3) / 4, 256, 0, stream>>>(xb, csr, rowstart, deg, mb);
    gemm_mfma4<<<gemm_grid, 256, 0, stream>>>(mb, xb, W1lb, b1l, W1rb, xb, 1);  // h1b in-place over xb

    // layer 2
    agg_bf16<<<(N_NODES + 3) / 4, 256, 0, stream>>>(xb, csr, rowstart, deg, mb);
    gemm_mfma4<<<gemm_grid, 256, 0, stream>>>(mb, xb, W2lb, b2l, W2rb, d_out, 0);
}